// Round 1
// baseline (262.167 us; speedup 1.0000x reference)
//
#include <hip/hip_runtime.h>
#include <hip/hip_bf16.h>
#include <cstdint>

typedef __bf16 bf16;
typedef __bf16 bf16x8 __attribute__((ext_vector_type(8)));
typedef float floatx4 __attribute__((ext_vector_type(4)));

// async global->LDS, 16B per lane. LDS dest must be wave-uniform base; HW adds lane*16.
__device__ __forceinline__ void gld_lds16(const bf16* g, bf16* l) {
    __builtin_amdgcn_global_load_lds(
        (const __attribute__((address_space(1))) unsigned int*)g,
        (__attribute__((address_space(3))) unsigned int*)l, 16, 0, 0);
}

// ---------------------------------------------------------------------------
// Weight fp32 -> bf16 conversion (4 x 512x512 matrices packed consecutively)
// ---------------------------------------------------------------------------
__global__ __launch_bounds__(256) void convert_weights(
    const float* __restrict__ wq, const float* __restrict__ wk,
    const float* __restrict__ wv, const float* __restrict__ wo,
    bf16* __restrict__ out)
{
    int i = blockIdx.x * 256 + threadIdx.x;   // 0 .. 4*262144-1
    int which = i >> 18;
    int off = i & 262143;
    const float* src = which == 0 ? wq : which == 1 ? wk : which == 2 ? wv : wo;
    out[i] = (bf16)src[off];
}

// ---------------------------------------------------------------------------
// GroupNorm: x [B=16, C=512, N=1024] fp32 -> hT [B, N, C] bf16 (transposed!)
// One block per (batch, group): 16 channels x 1024 positions = 16384 elems.
// ---------------------------------------------------------------------------
__global__ __launch_bounds__(256) void gn_kernel(
    const float* __restrict__ x, const float* __restrict__ gs,
    const float* __restrict__ gb, bf16* __restrict__ hT)
{
    const int b = blockIdx.x >> 5;
    const int g = blockIdx.x & 31;
    const int t = threadIdx.x;
    const int wave = t >> 6, lane = t & 63;
    const float* xb = x + ((long long)b * 512 + g * 16) * 1024;

    float s1 = 0.f, s2 = 0.f;
#pragma unroll 8
    for (int i = 0; i < 64; ++i) {
        float v = xb[i * 256 + t];
        s1 += v; s2 += v * v;
    }
#pragma unroll
    for (int m = 32; m; m >>= 1) {
        s1 += __shfl_xor(s1, m, 64);
        s2 += __shfl_xor(s2, m, 64);
    }
    __shared__ float red[2][4];
    __shared__ float stats[2];
    if (lane == 0) { red[0][wave] = s1; red[1][wave] = s2; }
    __syncthreads();
    if (t == 0) {
        float a = red[0][0] + red[0][1] + red[0][2] + red[0][3];
        float q = red[1][0] + red[1][1] + red[1][2] + red[1][3];
        float mu = a * (1.0f / 16384.0f);
        float var = q * (1.0f / 16384.0f) - mu * mu;
        stats[0] = mu;
        stats[1] = rsqrtf(var + 1e-5f);
    }
    __syncthreads();
    const float mu = stats[0], rs = stats[1];

    __shared__ float tile[256 * 17];   // [n_local 256][c_local 16] pad->17
    bf16* hb = hT + (long long)b * 1024 * 512 + g * 16;
#pragma unroll 1
    for (int chunk = 0; chunk < 4; ++chunk) {
        const int n0 = chunk * 256;
#pragma unroll
        for (int i = 0; i < 16; ++i) {
            float sc = gs[g * 16 + i];
            float bi = gb[g * 16 + i];
            float v = xb[i * 1024 + n0 + t];      // coalesced
            tile[t * 17 + i] = (v - mu) * rs * sc + bi;
        }
        __syncthreads();
#pragma unroll
        for (int p = 0; p < 2; ++p) {
            int nl = p * 128 + (t >> 1);
            int half = t & 1;
            const float* src = &tile[nl * 17 + half * 8];
            bf16x8 o;
#pragma unroll
            for (int e = 0; e < 8; ++e) o[e] = (bf16)src[e];
            *(bf16x8*)(hb + (long long)(n0 + nl) * 512 + half * 8) = o;  // 16B store
        }
        __syncthreads();
    }
}

// ---------------------------------------------------------------------------
// NT GEMM: C[m,n] = sum_k A[m,k] * B[n,k]   (both K-contiguous, lda=ldb=K)
// 128x128 tile, BK=32, 4 waves each 64x64 (4x4 grid of 16x16x32 MFMA).
// EPI: 0=+bias[col], 1=+bias[row], 2=*scale, 3=none, 4=+bias[row]+resid (fp32)
// ---------------------------------------------------------------------------
template <int EPI, typename OT>
__global__ __launch_bounds__(256, 2) void gemm_nt(
    const bf16* __restrict__ A, long long sA,
    const bf16* __restrict__ B, long long sB,
    OT* __restrict__ C, long long sC,
    int M, int N, int K,
    const float* __restrict__ bias,
    const float* __restrict__ resid, long long sR,
    float scale)
{
    __shared__ bf16 As[128 * 32];
    __shared__ bf16 Bs[128 * 32];
    const int tid = threadIdx.x;
    const int l = tid & 63;
    const int wave = tid >> 6;
    const int wm = wave >> 1, wn = wave & 1;
    const int bm = blockIdx.x, bn = blockIdx.y, b = blockIdx.z;

    const bf16* Ab = A + (long long)b * sA + (long long)bm * 128 * K;
    const bf16* Bb = B + (long long)b * sB + (long long)bn * 128 * K;

    // staging: chunk c = tid (rows 0..63) and tid+256 (rows 64..127); 16B each
    const int srow = tid >> 2;
    const int soff = (tid & 3) * 8;
    const bf16* ga = Ab + (long long)srow * K + soff;
    const bf16* gb2 = Bb + (long long)srow * K + soff;
    bf16* lA0 = As + wave * 512;          // wave-uniform; HW adds lane*16B
    bf16* lA1 = As + 2048 + wave * 512;
    bf16* lB0 = Bs + wave * 512;
    bf16* lB1 = Bs + 2048 + wave * 512;
    const long long half_jump = (long long)64 * K;

    int aoff[4], boff[4];
#pragma unroll
    for (int i = 0; i < 4; ++i) {
        aoff[i] = (wm * 64 + i * 16 + (l & 15)) * 32 + (l >> 4) * 8;
        boff[i] = (wn * 64 + i * 16 + (l & 15)) * 32 + (l >> 4) * 8;
    }

    floatx4 acc[4][4] = {};

    for (int k0 = 0; k0 < K; k0 += 32) {
        gld_lds16(ga + k0, lA0);
        gld_lds16(ga + half_jump + k0, lA1);
        gld_lds16(gb2 + k0, lB0);
        gld_lds16(gb2 + half_jump + k0, lB1);
        __syncthreads();   // compiler inserts vmcnt(0) drain before barrier

        bf16x8 af[4], bfr[4];
#pragma unroll
        for (int i = 0; i < 4; ++i) af[i] = *(const bf16x8*)(As + aoff[i]);
#pragma unroll
        for (int i = 0; i < 4; ++i) bfr[i] = *(const bf16x8*)(Bs + boff[i]);
#pragma unroll
        for (int i = 0; i < 4; ++i)
#pragma unroll
            for (int j = 0; j < 4; ++j)
                acc[i][j] = __builtin_amdgcn_mfma_f32_16x16x32_bf16(
                    af[i], bfr[j], acc[i][j], 0, 0, 0);
        __syncthreads();
    }

    // epilogue: C/D layout col=lane&15, row=(lane>>4)*4+reg
    const long long cb = (long long)b * sC;
#pragma unroll
    for (int i = 0; i < 4; ++i) {
        const int mrow = bm * 128 + wm * 64 + i * 16 + (l >> 4) * 4;
#pragma unroll
        for (int j = 0; j < 4; ++j) {
            const int ncol = bn * 128 + wn * 64 + j * 16 + (l & 15);
#pragma unroll
            for (int r = 0; r < 4; ++r) {
                const int row = mrow + r;
                float v = acc[i][j][r];
                if (EPI == 0) v += bias[ncol];
                if (EPI == 1) v += bias[row];
                if (EPI == 2) v *= scale;
                if (EPI == 4) v += bias[row] + resid[(long long)b * sR + (long long)row * N + ncol];
                C[cb + (long long)row * N + ncol] = (OT)v;
            }
        }
    }
}

// ---------------------------------------------------------------------------
// Row softmax in place on bf16 scores S [B*N rows, N=1024]
// ---------------------------------------------------------------------------
__global__ __launch_bounds__(256) void softmax_kernel(bf16* __restrict__ S)
{
    bf16* p = S + (long long)blockIdx.x * 1024;
    const int t = threadIdx.x;
    const int wave = t >> 6, lane = t & 63;
    float v[4];
#pragma unroll
    for (int i = 0; i < 4; ++i) v[i] = (float)p[t + i * 256];
    float m = fmaxf(fmaxf(v[0], v[1]), fmaxf(v[2], v[3]));
#pragma unroll
    for (int k = 32; k; k >>= 1) m = fmaxf(m, __shfl_xor(m, k, 64));
    __shared__ float redm[4];
    __shared__ float reds[4];
    if (lane == 0) redm[wave] = m;
    __syncthreads();
    m = fmaxf(fmaxf(redm[0], redm[1]), fmaxf(redm[2], redm[3]));
    float s = 0.f;
#pragma unroll
    for (int i = 0; i < 4; ++i) { v[i] = __expf(v[i] - m); s += v[i]; }
#pragma unroll
    for (int k = 32; k; k >>= 1) s += __shfl_xor(s, k, 64);
    if (lane == 0) reds[wave] = s;
    __syncthreads();
    s = reds[0] + reds[1] + reds[2] + reds[3];
    const float r = 1.0f / s;
#pragma unroll
    for (int i = 0; i < 4; ++i) p[t + i * 256] = (bf16)(v[i] * r);
}

// ---------------------------------------------------------------------------
extern "C" void kernel_launch(void* const* d_in, const int* in_sizes, int n_in,
                              void* d_out, int out_size, void* d_ws, size_t ws_size,
                              hipStream_t stream)
{
    const float* x  = (const float*)d_in[0];
    const float* gs = (const float*)d_in[1];
    const float* gb = (const float*)d_in[2];
    const float* wq = (const float*)d_in[3];
    const float* bq = (const float*)d_in[4];
    const float* wk = (const float*)d_in[5];
    const float* bk = (const float*)d_in[6];
    const float* wv = (const float*)d_in[7];
    const float* bv = (const float*)d_in[8];
    const float* wo = (const float*)d_in[9];
    const float* bo = (const float*)d_in[10];
    float* out = (float*)d_out;

    const size_t BNC = (size_t)16 * 1024 * 512;   // 8,388,608 elems
    bf16* ws  = (bf16*)d_ws;
    bf16* hT  = ws;            // [B, N, C]
    bf16* qT  = hT + BNC;      // [B, N, C]
    bf16* kT  = qT + BNC;      // [B, N, C]
    bf16* vv  = kT + BNC;      // [B, C, N]
    bf16* hvT = vv + BNC;      // [B, N, C]
    bf16* wqb = hvT + BNC;
    bf16* wkb = wqb + 262144;
    bf16* wvb = wkb + 262144;
    bf16* wob = wvb + 262144;
    bf16* S   = wob + 262144;  // [B, N, N] scores, softmaxed in place

    convert_weights<<<4096, 256, 0, stream>>>(wq, wk, wv, wo, wqb);
    gn_kernel<<<512, 256, 0, stream>>>(x, gs, gb, hT);

    // qT = hT . wq^T + bq   [1024 x 512], K=512
    gemm_nt<0, bf16><<<dim3(8, 4, 16), 256, 0, stream>>>(
        hT, 524288LL, wqb, 0LL, qT, 524288LL, 1024, 512, 512, bq, nullptr, 0LL, 1.0f);
    // kT = hT . wk^T + bk
    gemm_nt<0, bf16><<<dim3(8, 4, 16), 256, 0, stream>>>(
        hT, 524288LL, wkb, 0LL, kT, 524288LL, 1024, 512, 512, bk, nullptr, 0LL, 1.0f);
    // v = wv . hT^T + bv    [512 x 1024], K=512
    gemm_nt<1, bf16><<<dim3(4, 8, 16), 256, 0, stream>>>(
        wvb, 0LL, hT, 524288LL, vv, 524288LL, 512, 1024, 512, bv, nullptr, 0LL, 1.0f);
    // S = (qT . kT^T) / sqrt(C)   [1024 x 1024], K=512
    gemm_nt<2, bf16><<<dim3(8, 8, 16), 256, 0, stream>>>(
        qT, 524288LL, kT, 524288LL, S, 1048576LL, 1024, 1024, 512,
        nullptr, nullptr, 0LL, 0.044194173824159216f);
    // P = softmax rows
    softmax_kernel<<<16384, 256, 0, stream>>>(S);
    // hvT = P . v^T   [1024 x 512], K=1024
    gemm_nt<3, bf16><<<dim3(8, 4, 16), 256, 0, stream>>>(
        S, 1048576LL, vv, 524288LL, hvT, 524288LL, 1024, 512, 1024,
        nullptr, nullptr, 0LL, 1.0f);
    // out = wo . hvT^T + bo + x   [512 x 1024] fp32, K=512
    gemm_nt<4, float><<<dim3(4, 8, 16), 256, 0, stream>>>(
        wob, 0LL, hvT, 524288LL, out, 524288LL, 512, 1024, 512,
        bo, x, 524288LL, 1.0f);
}

// Round 2
// 252.777 us; speedup vs baseline: 1.0371x; 1.0371x over previous
//
#include <hip/hip_runtime.h>
#include <hip/hip_bf16.h>
#include <cstdint>

typedef __bf16 bf16;
typedef __bf16 bf16x8 __attribute__((ext_vector_type(8)));
typedef __bf16 bf16x4 __attribute__((ext_vector_type(4)));
typedef float floatx4 __attribute__((ext_vector_type(4)));

// async global->LDS, 16B per lane. LDS dest must be wave-uniform base; HW adds lane*16.
__device__ __forceinline__ void gld_lds16(const bf16* g, bf16* l) {
    __builtin_amdgcn_global_load_lds(
        (const __attribute__((address_space(1))) unsigned int*)g,
        (__attribute__((address_space(3))) unsigned int*)l, 16, 0, 0);
}

// ---------------------------------------------------------------------------
// Weight conversion: wq,wk,wv -> wqkv bf16 [1536,512]; wo -> wob bf16 [512,512];
// bq,bk,bv -> bqkv fp32 [1536].
// ---------------------------------------------------------------------------
__global__ __launch_bounds__(256) void convert_weights(
    const float* __restrict__ wq, const float* __restrict__ wk,
    const float* __restrict__ wv, const float* __restrict__ wo,
    const float* __restrict__ bq, const float* __restrict__ bk,
    const float* __restrict__ bv,
    bf16* __restrict__ wqkv, bf16* __restrict__ wob, float* __restrict__ bqkv)
{
    int i = blockIdx.x * 256 + threadIdx.x;   // 0 .. 1048575
    if (i < 786432) {
        int which = i >> 18;
        int off = i & 262143;
        const float* src = which == 0 ? wq : which == 1 ? wk : wv;
        wqkv[i] = (bf16)src[off];
    } else {
        wob[i - 786432] = (bf16)wo[i - 786432];
    }
    if (i < 1536)
        bqkv[i] = i < 512 ? bq[i] : (i < 1024 ? bk[i - 512] : bv[i - 1024]);
}

// ---------------------------------------------------------------------------
// GroupNorm: x [B=16, C=512, N=1024] fp32 -> hT [B, N, C] bf16 (transposed!)
// One block per (batch, group): 16 channels x 1024 positions.
// ---------------------------------------------------------------------------
__global__ __launch_bounds__(256) void gn_kernel(
    const float* __restrict__ x, const float* __restrict__ gs,
    const float* __restrict__ gb, bf16* __restrict__ hT)
{
    const int b = blockIdx.x >> 5;
    const int g = blockIdx.x & 31;
    const int t = threadIdx.x;
    const int wave = t >> 6, lane = t & 63;
    const float* xb = x + ((long long)b * 512 + g * 16) * 1024;
    const float4* x4 = (const float4*)xb;

    float s1 = 0.f, s2 = 0.f;
#pragma unroll
    for (int i = 0; i < 16; ++i) {
        float4 v = x4[i * 256 + t];
        s1 += v.x + v.y + v.z + v.w;
        s2 += v.x * v.x + v.y * v.y + v.z * v.z + v.w * v.w;
    }
#pragma unroll
    for (int m = 32; m; m >>= 1) {
        s1 += __shfl_xor(s1, m, 64);
        s2 += __shfl_xor(s2, m, 64);
    }
    __shared__ float red[2][4];
    __shared__ float stats[2];
    if (lane == 0) { red[0][wave] = s1; red[1][wave] = s2; }
    __syncthreads();
    if (t == 0) {
        float a = red[0][0] + red[0][1] + red[0][2] + red[0][3];
        float q = red[1][0] + red[1][1] + red[1][2] + red[1][3];
        float mu = a * (1.0f / 16384.0f);
        float var = q * (1.0f / 16384.0f) - mu * mu;
        stats[0] = mu;
        stats[1] = rsqrtf(var + 1e-5f);
    }
    __syncthreads();
    const float mu = stats[0], rs = stats[1];

    __shared__ float tile[256 * 17];   // [n_local 256][c_local 16] pad->17
    bf16* hb = hT + (long long)b * 1024 * 512 + g * 16;
#pragma unroll 1
    for (int chunk = 0; chunk < 4; ++chunk) {
        const int n0 = chunk * 256;
#pragma unroll
        for (int i = 0; i < 16; ++i) {
            float sc = gs[g * 16 + i];
            float bi = gb[g * 16 + i];
            float v = xb[i * 1024 + n0 + t];      // L2-hot re-read, coalesced
            tile[t * 17 + i] = (v - mu) * rs * sc + bi;
        }
        __syncthreads();
#pragma unroll
        for (int p = 0; p < 2; ++p) {
            int nl = p * 128 + (t >> 1);
            int half = t & 1;
            const float* src = &tile[nl * 17 + half * 8];
            bf16x8 o;
#pragma unroll
            for (int e = 0; e < 8; ++e) o[e] = (bf16)src[e];
            *(bf16x8*)(hb + (long long)(n0 + nl) * 512 + half * 8) = o;  // 16B store
        }
        __syncthreads();
    }
}

// ---------------------------------------------------------------------------
// NT GEMM: C[m,n] = sum_k A[m,k]*B[n,k], lda=ldb=K. 128x128 tile, BK=64.
// XOR-swizzled LDS (granule 8 bf16): LDS (row, g') holds global (row, g'^(row&7)).
// EPI: 0=+bias[col], 1=+bias[row], 2=*scale, 3=none, 4=+bias[row]+resid fp32,
//      5=fused QKV (C=q scaled, C2=k, C3=v transposed)
// ---------------------------------------------------------------------------
template <int EPI, typename OT>
__global__ __launch_bounds__(256, 2) void gemm_nt(
    const bf16* __restrict__ A, long long sA,
    const bf16* __restrict__ B, long long sB,
    OT* __restrict__ C, long long sC,
    OT* __restrict__ C2, OT* __restrict__ C3,
    int M, int N, int K,
    const float* __restrict__ bias,
    const float* __restrict__ resid, long long sR,
    float scale)
{
    __shared__ bf16 As[128 * 64];
    __shared__ bf16 Bs[128 * 64];
    const int tid = threadIdx.x;
    const int l = tid & 63;
    const int wave = tid >> 6;
    const int wm = wave >> 1, wn = wave & 1;
    const int bm = blockIdx.x, bn = blockIdx.y, b = blockIdx.z;

    const bf16* Ab = A + (long long)b * sA + (long long)bm * 128 * K;
    const bf16* Bb = B + (long long)b * sB + (long long)bn * 128 * K;

    // staging: lane l fetches global granule (l&7)^(l>>3) of row wave*8+(l>>3)
    // (+c*32 rows per call c), landing at LDS granule l&7 (linear order).
    const int swg = ((l & 7) ^ (l >> 3)) * 8;
    const bf16* ga  = Ab + (long long)(wave * 8 + (l >> 3)) * K + swg;
    const bf16* gbp = Bb + (long long)(wave * 8 + (l >> 3)) * K + swg;
    const long long c32 = (long long)32 * K;

    // fragment read offsets: A[m][k], k-granule g=ks*4+(l>>4), LDS g' = g^(m&7), m&7==l&7
    const int G0 = (((l >> 4) + 0) ^ (l & 7)) * 8;
    const int G1 = (((l >> 4) + 4) ^ (l & 7)) * 8;
    int arow[4], brow[4];
#pragma unroll
    for (int i = 0; i < 4; ++i) {
        arow[i] = (wm * 64 + i * 16 + (l & 15)) * 64;
        brow[i] = (wn * 64 + i * 16 + (l & 15)) * 64;
    }

    floatx4 acc[4][4] = {};

    for (int k0 = 0; k0 < K; k0 += 64) {
#pragma unroll
        for (int c = 0; c < 4; ++c)
            gld_lds16(ga + c * c32 + k0, As + (c * 32 + wave * 8) * 64);
#pragma unroll
        for (int c = 0; c < 4; ++c)
            gld_lds16(gbp + c * c32 + k0, Bs + (c * 32 + wave * 8) * 64);
        __syncthreads();

#pragma unroll
        for (int ks = 0; ks < 2; ++ks) {
            const int G = ks ? G1 : G0;
            bf16x8 af[4], bfr[4];
#pragma unroll
            for (int i = 0; i < 4; ++i) af[i] = *(const bf16x8*)(As + arow[i] + G);
#pragma unroll
            for (int i = 0; i < 4; ++i) bfr[i] = *(const bf16x8*)(Bs + brow[i] + G);
#pragma unroll
            for (int i = 0; i < 4; ++i)
#pragma unroll
                for (int j = 0; j < 4; ++j)
                    acc[i][j] = __builtin_amdgcn_mfma_f32_16x16x32_bf16(
                        af[i], bfr[j], acc[i][j], 0, 0, 0);
        }
        __syncthreads();
    }

    // epilogue: C/D layout col=lane&15, row=(lane>>4)*4+reg
    const long long cb = (long long)b * sC;
#pragma unroll
    for (int i = 0; i < 4; ++i) {
        const int mrow = bm * 128 + wm * 64 + i * 16 + (l >> 4) * 4;
#pragma unroll
        for (int j = 0; j < 4; ++j) {
            const int ncol = bn * 128 + wn * 64 + j * 16 + (l & 15);
#pragma unroll
            for (int r = 0; r < 4; ++r) {
                const int row = mrow + r;
                float v = acc[i][j][r];
                if (EPI == 0) v += bias[ncol];
                if (EPI == 1) v += bias[row];
                if (EPI == 2) v *= scale;
                if (EPI == 4) v += bias[row] + resid[(long long)b * sR + (long long)row * N + ncol];
                if (EPI == 5) {
                    const int which = bn >> 2;            // block-uniform: 0=q 1=k 2=v
                    v += bias[ncol];
                    const int lcol = ncol & 511;
                    if (which == 0)      C [cb + (long long)row * 512 + lcol] = (OT)(v * scale);
                    else if (which == 1) C2[cb + (long long)row * 512 + lcol] = (OT)v;
                    else                 C3[cb + (long long)lcol * 1024 + row] = (OT)v;
                } else {
                    C[cb + (long long)row * N + ncol] = (OT)v;
                }
            }
        }
    }
}

// ---------------------------------------------------------------------------
// Row softmax in place on bf16 scores S [B*N rows, N=1024]
// ---------------------------------------------------------------------------
__global__ __launch_bounds__(256) void softmax_kernel(bf16* __restrict__ S)
{
    bf16* p = S + (long long)blockIdx.x * 1024;
    const int t = threadIdx.x;
    const int wave = t >> 6, lane = t & 63;
    bf16x4 d = *(const bf16x4*)(p + 4 * t);
    float v[4];
#pragma unroll
    for (int i = 0; i < 4; ++i) v[i] = (float)d[i];
    float m = fmaxf(fmaxf(v[0], v[1]), fmaxf(v[2], v[3]));
#pragma unroll
    for (int k = 32; k; k >>= 1) m = fmaxf(m, __shfl_xor(m, k, 64));
    __shared__ float redm[4];
    __shared__ float reds[4];
    if (lane == 0) redm[wave] = m;
    __syncthreads();
    m = fmaxf(fmaxf(redm[0], redm[1]), fmaxf(redm[2], redm[3]));
    float s = 0.f;
#pragma unroll
    for (int i = 0; i < 4; ++i) { v[i] = __expf(v[i] - m); s += v[i]; }
#pragma unroll
    for (int k = 32; k; k >>= 1) s += __shfl_xor(s, k, 64);
    if (lane == 0) reds[wave] = s;
    __syncthreads();
    s = reds[0] + reds[1] + reds[2] + reds[3];
    const float r = 1.0f / s;
    bf16x4 o;
#pragma unroll
    for (int i = 0; i < 4; ++i) o[i] = (bf16)(v[i] * r);
    *(bf16x4*)(p + 4 * t) = o;
}

// ---------------------------------------------------------------------------
extern "C" void kernel_launch(void* const* d_in, const int* in_sizes, int n_in,
                              void* d_out, int out_size, void* d_ws, size_t ws_size,
                              hipStream_t stream)
{
    const float* x  = (const float*)d_in[0];
    const float* gs = (const float*)d_in[1];
    const float* gb = (const float*)d_in[2];
    const float* wq = (const float*)d_in[3];
    const float* bq = (const float*)d_in[4];
    const float* wk = (const float*)d_in[5];
    const float* bk = (const float*)d_in[6];
    const float* wv = (const float*)d_in[7];
    const float* bv = (const float*)d_in[8];
    const float* wo = (const float*)d_in[9];
    const float* bo = (const float*)d_in[10];
    float* out = (float*)d_out;

    const size_t BNC = (size_t)16 * 1024 * 512;   // 8,388,608 elems
    bf16* ws   = (bf16*)d_ws;
    bf16* hT   = ws;             // [B, N, C]; reused as hvT after QKV GEMM
    bf16* qT   = hT + BNC;       // [B, N, C] (pre-scaled by 1/sqrt(C))
    bf16* kT   = qT + BNC;       // [B, N, C]
    bf16* vv   = kT + BNC;       // [B, C, N]
    bf16* wqkv = vv + BNC;       // [1536, 512]
    bf16* wob  = wqkv + 786432;  // [512, 512]
    bf16* S    = wob + 262144;   // [B, N, N] scores, softmaxed in place
    float* bqkv = (float*)(S + (size_t)16 * 1024 * 1024);  // [1536]
    bf16* hvT  = hT;             // [B, N, C]

    convert_weights<<<4096, 256, 0, stream>>>(wq, wk, wv, wo, bq, bk, bv, wqkv, wob, bqkv);
    gn_kernel<<<512, 256, 0, stream>>>(x, gs, gb, hT);

    // fused qkv: [1024 x 1536] = hT . wqkv^T, K=512; q scaled by 1/sqrt(C), v transposed
    gemm_nt<5, bf16><<<dim3(8, 12, 16), 256, 0, stream>>>(
        hT, 524288LL, wqkv, 0LL, qT, 524288LL, kT, vv,
        1024, 1536, 512, bqkv, nullptr, 0LL, 0.044194173824159216f);
    // S = qT . kT^T   [1024 x 1024], K=512 (scale already folded into q)
    gemm_nt<3, bf16><<<dim3(8, 8, 16), 256, 0, stream>>>(
        qT, 524288LL, kT, 524288LL, S, 1048576LL, nullptr, nullptr,
        1024, 1024, 512, nullptr, nullptr, 0LL, 1.0f);
    // P = softmax rows
    softmax_kernel<<<16384, 256, 0, stream>>>(S);
    // hvT = P . v^T   [1024 x 512], K=1024
    gemm_nt<3, bf16><<<dim3(8, 4, 16), 256, 0, stream>>>(
        S, 1048576LL, vv, 524288LL, hvT, 524288LL, nullptr, nullptr,
        1024, 512, 1024, nullptr, nullptr, 0LL, 1.0f);
    // out = wo . hvT^T + bo + x   [512 x 1024] fp32, K=512
    gemm_nt<4, float><<<dim3(4, 8, 16), 256, 0, stream>>>(
        wob, 0LL, hvT, 524288LL, out, 524288LL, nullptr, nullptr,
        512, 1024, 512, bo, x, 524288LL, 1.0f);
}